// Round 4
// baseline (1112.405 us; speedup 1.0000x reference)
//
#include <hip/hip_runtime.h>

#define NT 512

typedef __attribute__((ext_vector_type(8))) short short8;
typedef __attribute__((ext_vector_type(4))) float f32x4;
typedef __attribute__((ext_vector_type(4))) unsigned short u16x4;

__device__ __forceinline__ unsigned short f2bf(float f) {
  unsigned int u = __builtin_bit_cast(unsigned int, f);
  u += 0x7fffu + ((u >> 16) & 1u);
  return (unsigned short)(u >> 16);
}

// Repack Wq (512x512), Wk (512x768), Wv (512x768) f32 -> bf16 fragments in
// MFMA operand order: frag[head][kk32][n][lane][8 shorts]. A B-fragment load
// is then lane*16B contiguous -> one coalesced 1KB wave load.
__global__ void cvt_weights(const float* __restrict__ wq,
                            const float* __restrict__ wk,
                            const float* __restrict__ wv,
                            unsigned short* __restrict__ o) {
  int stride = gridDim.x * blockDim.x;
  int i0 = blockIdx.x * blockDim.x + threadIdx.x;
  for (int t = i0; t < 32768; t += stride) {
    int lane = t & 63, n = (t >> 6) & 3, kk32 = (t >> 8) & 15, head = t >> 12;
    int row = head * 64 + n * 16 + (lane & 15);
    int k   = kk32 * 32 + (lane >> 4) * 8;
    const float* s = wq + (size_t)row * 512 + k;
    unsigned short* d = o + (size_t)t * 8;
    #pragma unroll
    for (int e = 0; e < 8; ++e) d[e] = f2bf(s[e]);
  }
  for (int t = i0; t < 49152; t += stride) {
    int lane = t & 63, n = (t >> 6) & 3, rem = t >> 8;
    int kk32 = rem % 24, head = rem / 24;
    int row = head * 64 + n * 16 + (lane & 15);
    int k   = kk32 * 32 + (lane >> 4) * 8;
    const float* s = wk + (size_t)row * 768 + k;
    unsigned short* d = o + 262144 + (size_t)t * 8;
    #pragma unroll
    for (int e = 0; e < 8; ++e) d[e] = f2bf(s[e]);
  }
  for (int t = i0; t < 49152; t += stride) {
    int lane = t & 63, n = (t >> 6) & 3, rem = t >> 8;
    int kk32 = rem % 24, head = rem / 24;
    int row = head * 64 + n * 16 + (lane & 15);
    int k   = kk32 * 32 + (lane >> 4) * 8;
    const float* s = wv + (size_t)row * 768 + k;
    unsigned short* d = o + 655360 + (size_t)t * 8;
    #pragma unroll
    for (int e = 0; e < 8; ++e) d[e] = f2bf(s[e]);
  }
}

// Block = 64 rows, 8 waves, wave == head. All x/xf rows prefetched to regs at
// start; LN from regs; bf16 chunks staged through a 2x32KB LDS double buffer
// (K-chunks of 256). k+v share one A sweep. B-fragments 1-deep prefetched.
__global__ __launch_bounds__(NT, 4)
void fused_xattn(const float* __restrict__ x, const float* __restrict__ xf,
                 const float* __restrict__ nw, const float* __restrict__ nb,
                 const float* __restrict__ tw, const float* __restrict__ tb,
                 const unsigned short* __restrict__ wbf,
                 float* __restrict__ out) {
  __shared__ __attribute__((aligned(16))) char smem[65536];  // 2 x [64][256] bf16
  const int tid   = threadIdx.x;
  const int lane  = tid & 63;
  const int wid   = tid >> 6;          // wave == head
  const int lr    = lane & 15;
  const int lkb   = (lane >> 4) * 8;   // k-offset within fragment
  const int lrow4 = (lane >> 4) * 4;   // C/D row base

  const long row0 = (long)blockIdx.x * 64;
  float* __restrict__ y1 = out;
  float* __restrict__ y2 = out + 16777216L;

  // ---- prefetch all inputs for this tile (40 x dwordx4 per lane in flight) --
  f32x4 xr[8][2];
  #pragma unroll
  for (int j = 0; j < 8; ++j) {
    const f32x4* rp = (const f32x4*)(x + (row0 + wid * 8 + j) * 512);
    xr[j][0] = rp[lane]; xr[j][1] = rp[lane + 64];
  }
  f32x4 fr[8][3];
  #pragma unroll
  for (int j = 0; j < 8; ++j) {
    const f32x4* rp = (const f32x4*)(xf + (row0 + wid * 8 + j) * 768);
    fr[j][0] = rp[lane]; fr[j][1] = rp[lane + 64]; fr[j][2] = rp[lane + 128];
  }

  // ---- LN(x) from regs -> bf16 regs ----------------------------------------
  u16x4 xb[8][2];
  {
    const f32x4* g4 = (const f32x4*)nw;
    const f32x4* b4 = (const f32x4*)nb;
    f32x4 g0 = g4[lane], g1 = g4[lane + 64];
    f32x4 c0 = b4[lane], c1 = b4[lane + 64];
    #pragma unroll
    for (int j = 0; j < 8; ++j) {
      f32x4 t0 = xr[j][0], t1 = xr[j][1];
      float s  = t0.x + t0.y + t0.z + t0.w + t1.x + t1.y + t1.z + t1.w;
      float s2 = t0.x*t0.x + t0.y*t0.y + t0.z*t0.z + t0.w*t0.w
               + t1.x*t1.x + t1.y*t1.y + t1.z*t1.z + t1.w*t1.w;
      #pragma unroll
      for (int m = 1; m < 64; m <<= 1) { s += __shfl_xor(s, m, 64); s2 += __shfl_xor(s2, m, 64); }
      float mean = s * (1.0f / 512.0f);
      float var  = s2 * (1.0f / 512.0f) - mean * mean;
      float rs   = rsqrtf(var + 1e-5f);
      xb[j][0] = u16x4{ f2bf((t0.x - mean) * rs * g0.x + c0.x),
                        f2bf((t0.y - mean) * rs * g0.y + c0.y),
                        f2bf((t0.z - mean) * rs * g0.z + c0.z),
                        f2bf((t0.w - mean) * rs * g0.w + c0.w) };
      xb[j][1] = u16x4{ f2bf((t1.x - mean) * rs * g1.x + c1.x),
                        f2bf((t1.y - mean) * rs * g1.y + c1.y),
                        f2bf((t1.z - mean) * rs * g1.z + c1.z),
                        f2bf((t1.w - mean) * rs * g1.w + c1.w) };
    }
  }
  // ---- LN(xf) from regs -> bf16 regs ---------------------------------------
  u16x4 fb[8][3];
  {
    const f32x4* g4 = (const f32x4*)tw;
    const f32x4* b4 = (const f32x4*)tb;
    f32x4 g0 = g4[lane], g1 = g4[lane + 64], g2 = g4[lane + 128];
    f32x4 c0 = b4[lane], c1 = b4[lane + 64], c2 = b4[lane + 128];
    #pragma unroll
    for (int j = 0; j < 8; ++j) {
      f32x4 t0 = fr[j][0], t1 = fr[j][1], t2 = fr[j][2];
      float s  = t0.x + t0.y + t0.z + t0.w + t1.x + t1.y + t1.z + t1.w
               + t2.x + t2.y + t2.z + t2.w;
      float s2 = t0.x*t0.x + t0.y*t0.y + t0.z*t0.z + t0.w*t0.w
               + t1.x*t1.x + t1.y*t1.y + t1.z*t1.z + t1.w*t1.w
               + t2.x*t2.x + t2.y*t2.y + t2.z*t2.z + t2.w*t2.w;
      #pragma unroll
      for (int m = 1; m < 64; m <<= 1) { s += __shfl_xor(s, m, 64); s2 += __shfl_xor(s2, m, 64); }
      float mean = s * (1.0f / 768.0f);
      float var  = s2 * (1.0f / 768.0f) - mean * mean;
      float rs   = rsqrtf(var + 1e-5f);
      fb[j][0] = u16x4{ f2bf((t0.x - mean) * rs * g0.x + c0.x),
                        f2bf((t0.y - mean) * rs * g0.y + c0.y),
                        f2bf((t0.z - mean) * rs * g0.z + c0.z),
                        f2bf((t0.w - mean) * rs * g0.w + c0.w) };
      fb[j][1] = u16x4{ f2bf((t1.x - mean) * rs * g1.x + c1.x),
                        f2bf((t1.y - mean) * rs * g1.y + c1.y),
                        f2bf((t1.z - mean) * rs * g1.z + c1.z),
                        f2bf((t1.w - mean) * rs * g1.w + c1.w) };
      fb[j][2] = u16x4{ f2bf((t2.x - mean) * rs * g2.x + c2.x),
                        f2bf((t2.y - mean) * rs * g2.y + c2.y),
                        f2bf((t2.z - mean) * rs * g2.z + c2.z),
                        f2bf((t2.w - mean) * rs * g2.w + c2.w) };
    }
  }

  // chunk write: rows wid*8+j, 8B per lane, XOR-swizzled [64][256] bf16 buffer
#define WRITEC(buf, arr, c)                                                    \
  {                                                                            \
    _Pragma("unroll")                                                          \
    for (int j = 0; j < 8; ++j) {                                              \
      int row = wid * 8 + j;                                                   \
      int off = (row * 512 + lane * 8) ^ ((row & 7) << 4);                     \
      *(u16x4*)(smem + (buf) * 32768 + off) = arr[j][c];                       \
    }                                                                          \
  }

  f32x4 qa[4][4] = {};
#define QGEMM(buf, c)                                                          \
  {                                                                            \
    const unsigned short* bq = wbf + wid * 32768 + lane * 8;                   \
    short8 bc[4];                                                              \
    _Pragma("unroll")                                                          \
    for (int n = 0; n < 4; ++n)                                                \
      bc[n] = *(const short8*)(bq + ((c) * 8) * 2048 + n * 512);               \
    _Pragma("unroll")                                                          \
    for (int kk = 0; kk < 8; ++kk) {                                           \
      short8 a[4];                                                             \
      _Pragma("unroll")                                                        \
      for (int m = 0; m < 4; ++m) {                                            \
        int row = m * 16 + lr;                                                 \
        int off = (row * 512 + (kk * 32 + lkb) * 2) ^ ((row & 7) << 4);        \
        a[m] = *(const short8*)(smem + (buf) * 32768 + off);                   \
      }                                                                        \
      short8 bn[4];                                                            \
      if (kk < 7) {                                                            \
        _Pragma("unroll")                                                      \
        for (int n = 0; n < 4; ++n)                                            \
          bn[n] = *(const short8*)(bq + ((c) * 8 + kk + 1) * 2048 + n * 512);  \
      }                                                                        \
      _Pragma("unroll")                                                        \
      for (int n = 0; n < 4; ++n)                                              \
        _Pragma("unroll")                                                      \
        for (int m = 0; m < 4; ++m)                                            \
          qa[m][n] = __builtin_amdgcn_mfma_f32_16x16x32_bf16(a[m], bc[n], qa[m][n], 0, 0, 0); \
      if (kk < 7) {                                                            \
        _Pragma("unroll")                                                      \
        for (int n = 0; n < 4; ++n) bc[n] = bn[n];                             \
      }                                                                        \
    }                                                                          \
  }

  f32x4 ka[4][4] = {}, va[4][4] = {};
#define KVGEMM(buf, c)                                                         \
  {                                                                            \
    const unsigned short* bk = wbf + 262144 + wid * 49152 + lane * 8;          \
    const unsigned short* bv = wbf + 655360 + wid * 49152 + lane * 8;          \
    short8 kc[4], vc[4];                                                       \
    _Pragma("unroll")                                                          \
    for (int n = 0; n < 4; ++n) {                                              \
      kc[n] = *(const short8*)(bk + ((c) * 8) * 2048 + n * 512);               \
      vc[n] = *(const short8*)(bv + ((c) * 8) * 2048 + n * 512);               \
    }                                                                          \
    _Pragma("unroll")                                                          \
    for (int kk = 0; kk < 8; ++kk) {                                           \
      short8 a[4];                                                             \
      _Pragma("unroll")                                                        \
      for (int m = 0; m < 4; ++m) {                                            \
        int row = m * 16 + lr;                                                 \
        int off = (row * 512 + (kk * 32 + lkb) * 2) ^ ((row & 7) << 4);        \
        a[m] = *(const short8*)(smem + (buf) * 32768 + off);                   \
      }                                                                        \
      short8 kn[4], vn[4];                                                     \
      if (kk < 7) {                                                            \
        _Pragma("unroll")                                                      \
        for (int n = 0; n < 4; ++n) {                                          \
          kn[n] = *(const short8*)(bk + ((c) * 8 + kk + 1) * 2048 + n * 512);  \
          vn[n] = *(const short8*)(bv + ((c) * 8 + kk + 1) * 2048 + n * 512);  \
        }                                                                      \
      }                                                                        \
      _Pragma("unroll")                                                        \
      for (int n = 0; n < 4; ++n)                                              \
        _Pragma("unroll")                                                      \
        for (int m = 0; m < 4; ++m) {                                          \
          ka[m][n] = __builtin_amdgcn_mfma_f32_16x16x32_bf16(a[m], kc[n], ka[m][n], 0, 0, 0); \
          va[m][n] = __builtin_amdgcn_mfma_f32_16x16x32_bf16(a[m], vc[n], va[m][n], 0, 0, 0); \
        }                                                                      \
      if (kk < 7) {                                                            \
        _Pragma("unroll")                                                      \
        for (int n = 0; n < 4; ++n) { kc[n] = kn[n]; vc[n] = vn[n]; }          \
      }                                                                        \
    }                                                                          \
  }

  // ---- double-buffered chunk schedule: x0,x1 (q) then xf0,xf1,xf2 (k+v) ----
  WRITEC(0, xb, 0);
  __syncthreads();
  WRITEC(1, xb, 1);
  QGEMM(0, 0);
  __syncthreads();
  WRITEC(0, fb, 0);
  QGEMM(1, 1);
  __syncthreads();
  WRITEC(1, fb, 1);
  KVGEMM(0, 0);
  __syncthreads();
  WRITEC(0, fb, 2);
  KVGEMM(1, 1);
  __syncthreads();
  KVGEMM(0, 2);

  // ---- gate: w[row,h] = (q.k)/8 over the wave's 64 channels -----------------
  float wgt[4][4];
  #pragma unroll
  for (int m = 0; m < 4; ++m) {
    #pragma unroll
    for (int r = 0; r < 4; ++r) {
      float p = 0.0f;
      #pragma unroll
      for (int n = 0; n < 4; ++n) p += qa[m][n][r] * ka[m][n][r];
      #pragma unroll
      for (int msk = 1; msk < 16; msk <<= 1) p += __shfl_xor(p, msk, 64);
      wgt[m][r] = p * 0.125f;   // 1/sqrt(64)
    }
  }

  // ---- y1 = (1-w)*q ; y2 = w*v ---------------------------------------------
  #pragma unroll
  for (int m = 0; m < 4; ++m) {
    #pragma unroll
    for (int r = 0; r < 4; ++r) {
      float f = 1.0f - wgt[m][r];
      long grow = row0 + m * 16 + lrow4 + r;
      #pragma unroll
      for (int n = 0; n < 4; ++n) {
        int ch = wid * 64 + n * 16 + lr;
        y1[grow * 512 + ch] = f * qa[m][n][r];
      }
    }
  }
  #pragma unroll
  for (int m = 0; m < 4; ++m) {
    #pragma unroll
    for (int r = 0; r < 4; ++r) {
      float f = wgt[m][r];
      long grow = row0 + m * 16 + lrow4 + r;
      #pragma unroll
      for (int n = 0; n < 4; ++n) {
        int ch = wid * 64 + n * 16 + lr;
        y2[grow * 512 + ch] = f * va[m][n][r];
      }
    }
  }
#undef WRITEC
#undef QGEMM
#undef KVGEMM
}

extern "C" void kernel_launch(void* const* d_in, const int* in_sizes, int n_in,
                              void* d_out, int out_size, void* d_ws, size_t ws_size,
                              hipStream_t stream) {
  const float* x  = (const float*)d_in[0];
  const float* xf = (const float*)d_in[1];
  const float* nw = (const float*)d_in[2];
  const float* nb = (const float*)d_in[3];
  const float* tw = (const float*)d_in[4];
  const float* tb = (const float*)d_in[5];
  const float* wq = (const float*)d_in[6];
  const float* wk = (const float*)d_in[7];
  const float* wv = (const float*)d_in[8];
  unsigned short* wbf = (unsigned short*)d_ws;   // 2 MB bf16 packed weights

  cvt_weights<<<256, 256, 0, stream>>>(wq, wk, wv, wbf);
  fused_xattn<<<512, NT, 0, stream>>>(x, xf, nw, nb, tw, tb, wbf, (float*)d_out);
}

// Round 5
// 117.238 us; speedup vs baseline: 9.4884x; 9.4884x over previous
//
#include <hip/hip_runtime.h>

#define NT 512
#define MT 64   // rows per block, 1 block/CU, 8 waves, wave == head

typedef __attribute__((ext_vector_type(8))) short short8;
typedef __attribute__((ext_vector_type(4))) float f32x4;
typedef __attribute__((ext_vector_type(4))) unsigned short u16x4;

__device__ __forceinline__ unsigned short f2bf(float f) {
  unsigned int u = __builtin_bit_cast(unsigned int, f);
  u += 0x7fffu + ((u >> 16) & 1u);
  return (unsigned short)(u >> 16);
}

// Repack Wq (512x512), Wk (512x768), Wv (512x768) f32 -> bf16 fragments in
// MFMA operand order: frag[head][kk32][n][lane][8 shorts] -> B-fragment load
// is lane*16B contiguous: one coalesced 1KB wave load.
__global__ void cvt_weights(const float* __restrict__ wq,
                            const float* __restrict__ wk,
                            const float* __restrict__ wv,
                            unsigned short* __restrict__ o) {
  int stride = gridDim.x * blockDim.x;
  int i0 = blockIdx.x * blockDim.x + threadIdx.x;
  for (int t = i0; t < 32768; t += stride) {
    int lane = t & 63, n = (t >> 6) & 3, kk32 = (t >> 8) & 15, head = t >> 12;
    int row = head * 64 + n * 16 + (lane & 15);
    int k   = kk32 * 32 + (lane >> 4) * 8;
    const float* s = wq + (size_t)row * 512 + k;
    unsigned short* d = o + (size_t)t * 8;
    #pragma unroll
    for (int e = 0; e < 8; ++e) d[e] = f2bf(s[e]);
  }
  for (int t = i0; t < 49152; t += stride) {
    int lane = t & 63, n = (t >> 6) & 3, rem = t >> 8;
    int kk32 = rem % 24, head = rem / 24;
    int row = head * 64 + n * 16 + (lane & 15);
    int k   = kk32 * 32 + (lane >> 4) * 8;
    const float* s = wk + (size_t)row * 768 + k;
    unsigned short* d = o + 262144 + (size_t)t * 8;
    #pragma unroll
    for (int e = 0; e < 8; ++e) d[e] = f2bf(s[e]);
  }
  for (int t = i0; t < 49152; t += stride) {
    int lane = t & 63, n = (t >> 6) & 3, rem = t >> 8;
    int kk32 = rem % 24, head = rem / 24;
    int row = head * 64 + n * 16 + (lane & 15);
    int k   = kk32 * 32 + (lane >> 4) * 8;
    const float* s = wv + (size_t)row * 768 + k;
    unsigned short* d = o + 655360 + (size_t)t * 8;
    #pragma unroll
    for (int e = 0; e < 8; ++e) d[e] = f2bf(s[e]);
  }
}

// 64 rows/block, 1 block/CU (256-reg budget). Batch-issued staging loads,
// xf loads hidden under q GEMM, 1-deep A/B prefetch in all GEMMs.
__global__ __launch_bounds__(NT, 2)
void fused_xattn(const float* __restrict__ x, const float* __restrict__ xf,
                 const float* __restrict__ nw, const float* __restrict__ nb,
                 const float* __restrict__ tw, const float* __restrict__ tb,
                 const unsigned short* __restrict__ wbf,
                 float* __restrict__ out) {
  __shared__ __attribute__((aligned(16))) char smem[98304];  // 64x768 bf16 (xf) / 64x512 (x)
  const int tid   = threadIdx.x;
  const int lane  = tid & 63;
  const int wid   = tid >> 6;          // wave == head
  const int lr    = lane & 15;
  const int lkb   = (lane >> 4) * 8;
  const int lrow4 = (lane >> 4) * 4;

  const long row0 = (long)blockIdx.x * MT;
  float* __restrict__ y1 = out;
  float* __restrict__ y2 = out + 16777216L;

  // ================= stage LN(x): batch-issue 16 loads, then LN, LDS =========
  {
    f32x4 t0[8], t1[8];
    #pragma unroll
    for (int j = 0; j < 8; ++j) {
      const f32x4* rp = (const f32x4*)(x + (row0 + wid + 8 * j) * 512);
      t0[j] = rp[lane]; t1[j] = rp[lane + 64];
    }
    const f32x4* g4 = (const f32x4*)nw;
    const f32x4* b4 = (const f32x4*)nb;
    f32x4 g0 = g4[lane], g1 = g4[lane + 64];
    f32x4 c0 = b4[lane], c1 = b4[lane + 64];
    #pragma unroll
    for (int j = 0; j < 8; ++j) {
      f32x4 a = t0[j], b = t1[j];
      float s  = a.x + a.y + a.z + a.w + b.x + b.y + b.z + b.w;
      float s2 = a.x*a.x + a.y*a.y + a.z*a.z + a.w*a.w
               + b.x*b.x + b.y*b.y + b.z*b.z + b.w*b.w;
      #pragma unroll
      for (int m = 1; m < 64; m <<= 1) { s += __shfl_xor(s, m, 64); s2 += __shfl_xor(s2, m, 64); }
      float mean = s * (1.0f / 512.0f);
      float var  = s2 * (1.0f / 512.0f) - mean * mean;
      float rs   = rsqrtf(var + 1e-5f);
      u16x4 o0 = { f2bf((a.x - mean) * rs * g0.x + c0.x),
                   f2bf((a.y - mean) * rs * g0.y + c0.y),
                   f2bf((a.z - mean) * rs * g0.z + c0.z),
                   f2bf((a.w - mean) * rs * g0.w + c0.w) };
      u16x4 o1 = { f2bf((b.x - mean) * rs * g1.x + c1.x),
                   f2bf((b.y - mean) * rs * g1.y + c1.y),
                   f2bf((b.z - mean) * rs * g1.z + c1.z),
                   f2bf((b.w - mean) * rs * g1.w + c1.w) };
      int r = wid + 8 * j;
      int base = r * 1024, sw = (r & 7) << 4;
      *(u16x4*)(smem + ((base +       lane * 8) ^ sw)) = o0;
      *(u16x4*)(smem + ((base + 512 + lane * 8) ^ sw)) = o1;
    }
  }
  __syncthreads();

  // ---- issue xf loads NOW (latency hides under q GEMM); 96 regs held --------
  f32x4 fr0[8], fr1[8], fr2[8];
  #pragma unroll
  for (int j = 0; j < 8; ++j) {
    const f32x4* rp = (const f32x4*)(xf + (row0 + wid + 8 * j) * 768);
    fr0[j] = rp[lane]; fr1[j] = rp[lane + 64]; fr2[j] = rp[lane + 128];
  }

  // ================= q GEMM: K=512, 1-deep A/B prefetch ======================
  f32x4 qa[4][4] = {};
  {
    const unsigned short* bq = wbf + wid * 32768 + lane * 8;
    short8 bc[4], ac[4];
    #pragma unroll
    for (int n = 0; n < 4; ++n) bc[n] = *(const short8*)(bq + n * 512);
    #pragma unroll
    for (int m = 0; m < 4; ++m) {
      int row = m * 16 + lr;
      ac[m] = *(const short8*)(smem + ((row * 1024 + lkb * 2) ^ ((row & 7) << 4)));
    }
    for (int kk = 0; kk < 16; ++kk) {
      short8 bn[4], an[4];
      if (kk < 15) {
        #pragma unroll
        for (int n = 0; n < 4; ++n)
          bn[n] = *(const short8*)(bq + (kk + 1) * 2048 + n * 512);
        #pragma unroll
        for (int m = 0; m < 4; ++m) {
          int row = m * 16 + lr;
          an[m] = *(const short8*)(smem + ((row * 1024 + ((kk + 1) * 32 + lkb) * 2) ^ ((row & 7) << 4)));
        }
      }
      #pragma unroll
      for (int n = 0; n < 4; ++n)
        #pragma unroll
        for (int m = 0; m < 4; ++m)
          qa[m][n] = __builtin_amdgcn_mfma_f32_16x16x32_bf16(ac[m], bc[n], qa[m][n], 0, 0, 0);
      if (kk < 15) {
        #pragma unroll
        for (int n = 0; n < 4; ++n) bc[n] = bn[n];
        #pragma unroll
        for (int m = 0; m < 4; ++m) ac[m] = an[m];
      }
    }
  }
  __syncthreads();   // done reading x tile

  // ================= LN(xf) from regs -> LDS ================================
  {
    const f32x4* g4 = (const f32x4*)tw;
    const f32x4* b4 = (const f32x4*)tb;
    f32x4 g0 = g4[lane], g1 = g4[lane + 64], g2 = g4[lane + 128];
    f32x4 c0 = b4[lane], c1 = b4[lane + 64], c2 = b4[lane + 128];
    #pragma unroll
    for (int j = 0; j < 8; ++j) {
      f32x4 a = fr0[j], b = fr1[j], c = fr2[j];
      float s  = a.x + a.y + a.z + a.w + b.x + b.y + b.z + b.w
               + c.x + c.y + c.z + c.w;
      float s2 = a.x*a.x + a.y*a.y + a.z*a.z + a.w*a.w
               + b.x*b.x + b.y*b.y + b.z*b.z + b.w*b.w
               + c.x*c.x + c.y*c.y + c.z*c.z + c.w*c.w;
      #pragma unroll
      for (int m = 1; m < 64; m <<= 1) { s += __shfl_xor(s, m, 64); s2 += __shfl_xor(s2, m, 64); }
      float mean = s * (1.0f / 768.0f);
      float var  = s2 * (1.0f / 768.0f) - mean * mean;
      float rs   = rsqrtf(var + 1e-5f);
      u16x4 o0 = { f2bf((a.x - mean) * rs * g0.x + c0.x),
                   f2bf((a.y - mean) * rs * g0.y + c0.y),
                   f2bf((a.z - mean) * rs * g0.z + c0.z),
                   f2bf((a.w - mean) * rs * g0.w + c0.w) };
      u16x4 o1 = { f2bf((b.x - mean) * rs * g1.x + c1.x),
                   f2bf((b.y - mean) * rs * g1.y + c1.y),
                   f2bf((b.z - mean) * rs * g1.z + c1.z),
                   f2bf((b.w - mean) * rs * g1.w + c1.w) };
      u16x4 o2 = { f2bf((c.x - mean) * rs * g2.x + c2.x),
                   f2bf((c.y - mean) * rs * g2.y + c2.y),
                   f2bf((c.z - mean) * rs * g2.z + c2.z),
                   f2bf((c.w - mean) * rs * g2.w + c2.w) };
      int r = wid + 8 * j;
      int base = r * 1536, sw = (r & 7) << 4;
      *(u16x4*)(smem + ((base +        lane * 8) ^ sw)) = o0;
      *(u16x4*)(smem + ((base + 512  + lane * 8) ^ sw)) = o1;
      *(u16x4*)(smem + ((base + 1024 + lane * 8) ^ sw)) = o2;
    }
  }
  __syncthreads();

  // ================= k GEMM: K=768, 1-deep A/B prefetch ======================
  f32x4 ka[4][4] = {};
  {
    const unsigned short* bk = wbf + 262144 + wid * 49152 + lane * 8;
    short8 bc[4], ac[4];
    #pragma unroll
    for (int n = 0; n < 4; ++n) bc[n] = *(const short8*)(bk + n * 512);
    #pragma unroll
    for (int m = 0; m < 4; ++m) {
      int row = m * 16 + lr;
      ac[m] = *(const short8*)(smem + ((row * 1536 + lkb * 2) ^ ((row & 7) << 4)));
    }
    for (int kk = 0; kk < 24; ++kk) {
      short8 bn[4], an[4];
      if (kk < 23) {
        #pragma unroll
        for (int n = 0; n < 4; ++n)
          bn[n] = *(const short8*)(bk + (kk + 1) * 2048 + n * 512);
        #pragma unroll
        for (int m = 0; m < 4; ++m) {
          int row = m * 16 + lr;
          an[m] = *(const short8*)(smem + ((row * 1536 + ((kk + 1) * 32 + lkb) * 2) ^ ((row & 7) << 4)));
        }
      }
      #pragma unroll
      for (int n = 0; n < 4; ++n)
        #pragma unroll
        for (int m = 0; m < 4; ++m)
          ka[m][n] = __builtin_amdgcn_mfma_f32_16x16x32_bf16(ac[m], bc[n], ka[m][n], 0, 0, 0);
      if (kk < 23) {
        #pragma unroll
        for (int n = 0; n < 4; ++n) bc[n] = bn[n];
        #pragma unroll
        for (int m = 0; m < 4; ++m) ac[m] = an[m];
      }
    }
  }

  // ================= gate + y1 = (1-w)*q =====================================
  float wgt[4][4];
  #pragma unroll
  for (int m = 0; m < 4; ++m) {
    #pragma unroll
    for (int r = 0; r < 4; ++r) {
      float p = 0.0f;
      #pragma unroll
      for (int n = 0; n < 4; ++n) p += qa[m][n][r] * ka[m][n][r];
      #pragma unroll
      for (int msk = 1; msk < 16; msk <<= 1) p += __shfl_xor(p, msk, 64);
      wgt[m][r] = p * 0.125f;   // 1/sqrt(64)
    }
  }
  #pragma unroll
  for (int m = 0; m < 4; ++m) {
    #pragma unroll
    for (int r = 0; r < 4; ++r) {
      float f = 1.0f - wgt[m][r];
      long grow = row0 + m * 16 + lrow4 + r;
      #pragma unroll
      for (int n = 0; n < 4; ++n) {
        int ch = wid * 64 + n * 16 + lr;
        y1[grow * 512 + ch] = f * qa[m][n][r];
      }
    }
  }

  // ================= v GEMM: K=768, then y2 = w*v ============================
  f32x4 va[4][4] = {};
  {
    const unsigned short* bv = wbf + 655360 + wid * 49152 + lane * 8;
    short8 bc[4], ac[4];
    #pragma unroll
    for (int n = 0; n < 4; ++n) bc[n] = *(const short8*)(bv + n * 512);
    #pragma unroll
    for (int m = 0; m < 4; ++m) {
      int row = m * 16 + lr;
      ac[m] = *(const short8*)(smem + ((row * 1536 + lkb * 2) ^ ((row & 7) << 4)));
    }
    for (int kk = 0; kk < 24; ++kk) {
      short8 bn[4], an[4];
      if (kk < 23) {
        #pragma unroll
        for (int n = 0; n < 4; ++n)
          bn[n] = *(const short8*)(bv + (kk + 1) * 2048 + n * 512);
        #pragma unroll
        for (int m = 0; m < 4; ++m) {
          int row = m * 16 + lr;
          an[m] = *(const short8*)(smem + ((row * 1536 + ((kk + 1) * 32 + lkb) * 2) ^ ((row & 7) << 4)));
        }
      }
      #pragma unroll
      for (int n = 0; n < 4; ++n)
        #pragma unroll
        for (int m = 0; m < 4; ++m)
          va[m][n] = __builtin_amdgcn_mfma_f32_16x16x32_bf16(ac[m], bc[n], va[m][n], 0, 0, 0);
      if (kk < 23) {
        #pragma unroll
        for (int n = 0; n < 4; ++n) bc[n] = bn[n];
        #pragma unroll
        for (int m = 0; m < 4; ++m) ac[m] = an[m];
      }
    }
  }
  #pragma unroll
  for (int m = 0; m < 4; ++m) {
    #pragma unroll
    for (int r = 0; r < 4; ++r) {
      float f = wgt[m][r];
      long grow = row0 + m * 16 + lrow4 + r;
      #pragma unroll
      for (int n = 0; n < 4; ++n) {
        int ch = wid * 64 + n * 16 + lr;
        y2[grow * 512 + ch] = f * va[m][n][r];
      }
    }
  }
}

extern "C" void kernel_launch(void* const* d_in, const int* in_sizes, int n_in,
                              void* d_out, int out_size, void* d_ws, size_t ws_size,
                              hipStream_t stream) {
  const float* x  = (const float*)d_in[0];
  const float* xf = (const float*)d_in[1];
  const float* nw = (const float*)d_in[2];
  const float* nb = (const float*)d_in[3];
  const float* tw = (const float*)d_in[4];
  const float* tb = (const float*)d_in[5];
  const float* wq = (const float*)d_in[6];
  const float* wk = (const float*)d_in[7];
  const float* wv = (const float*)d_in[8];
  unsigned short* wbf = (unsigned short*)d_ws;   // 2 MB bf16 packed weights

  cvt_weights<<<256, 256, 0, stream>>>(wq, wk, wv, wbf);
  fused_xattn<<<512, NT, 0, stream>>>(x, xf, nw, nb, tw, tb, wbf, (float*)d_out);
}